// Round 12
// baseline (977.720 us; speedup 1.0000x reference)
//
#include <hip/hip_runtime.h>
#include <hip/hip_bf16.h>
#include <cstddef>

// ---------------------------------------------------------------------------
// 3-layer GAT (PyG-style) on MI355X.
// Round 12: revert round-8 prefetch (VGPR 196 -> occupancy cliff, 222us).
// Keep round-7 fused gemm_al staging, but tile BM 128->64 so grid doubles
// (6 blocks/CU): barrier waits overlap across blocks instead of via ILP.
// __launch_bounds__(256,4) caps VGPR at 128 (the measured cliff).
// h stored fp16 (gather at the 8-XCD private-L2 re-fetch floor, ~213MB).
// ---------------------------------------------------------------------------

typedef _Float16 h4 __attribute__((ext_vector_type(4)));

#define ECAP 96  // LDS-cached logits per node; deg>ECAP falls back to re-gather

// ---------------- CSR build ----------------

__global__ void zero_i32(int* __restrict__ p, int n) {
  int i = blockIdx.x * 256 + threadIdx.x;
  if (i < n) p[i] = 0;
}

__global__ void edge_histogram(const int* __restrict__ ei, int E, int nnodes,
                               int* __restrict__ counts) {
  int e = blockIdx.x * 256 + threadIdx.x;
  int tot = E + nnodes;
  if (e >= tot) return;
  int dst = (e < E) ? ei[E + e] : (e - E);
  atomicAdd(&counts[dst], 1);
}

__global__ void scan_block(const int* __restrict__ in, int* __restrict__ out,
                           int* __restrict__ sums, int n) {
  __shared__ int tmp[256];
  int i = blockIdx.x * 256 + threadIdx.x;
  int v = (i < n) ? in[i] : 0;
  tmp[threadIdx.x] = v;
  __syncthreads();
  for (int off = 1; off < 256; off <<= 1) {
    int t = (threadIdx.x >= off) ? tmp[threadIdx.x - off] : 0;
    __syncthreads();
    tmp[threadIdx.x] += t;
    __syncthreads();
  }
  if (i < n) out[i] = tmp[threadIdx.x] - v;  // exclusive
  if (sums && threadIdx.x == 255) sums[blockIdx.x] = tmp[255];
}

__global__ void add_offsets(int* __restrict__ row_ptr, const int* __restrict__ offs,
                            int* __restrict__ nextp, int n, int total) {
  int i = blockIdx.x * 256 + threadIdx.x;
  if (i < n) {
    int v = row_ptr[i] + offs[blockIdx.x];
    row_ptr[i] = v;
    nextp[i] = v;
  }
  if (i == 0) row_ptr[n] = total;
}

__global__ void edge_scatter(const int* __restrict__ ei, int E, int nnodes,
                             int* __restrict__ nextp, int* __restrict__ col_idx) {
  int e = blockIdx.x * 256 + threadIdx.x;
  int tot = E + nnodes;
  if (e >= tot) return;
  int src = (e < E) ? ei[e] : (e - E);
  int dst = (e < E) ? ei[E + e] : (e - E);
  int pos = atomicAdd(&nextp[dst], 1);
  col_idx[pos] = src;
}

// ---------------- fused GEMM + al: h16 = A@B (fp32 math), al_s/al_d --------
// N fixed at 256, BM=64, BN=128, KB=16, 256 threads, 4x8 per thread.
// Direct LDS staging (round-7 structure). Block (bx,by) owns heads
// {2by, 2by+1} entirely -> al via 16-lane shuffle reduce in the epilogue.

__global__ __launch_bounds__(256, 4) void gemm_al(
    const float* __restrict__ A, const float* __restrict__ B,
    _Float16* __restrict__ C16, const float* __restrict__ a_src,
    const float* __restrict__ a_dst, float* __restrict__ alS,
    float* __restrict__ alD, int M, int K) {
  __shared__ float As[16][64 + 4];
  __shared__ float Bs[16][128];
  int t = threadIdx.x;
  int m0 = blockIdx.x * 64;
  int by = blockIdx.y;
  int n0 = by * 128;
  int tx = t & 15, ty = t >> 4;

  float c[2][4][4];  // [col-half][row i][col j]
#pragma unroll
  for (int b = 0; b < 2; ++b)
#pragma unroll
    for (int i = 0; i < 4; ++i)
#pragma unroll
      for (int j = 0; j < 4; ++j) c[b][i][j] = 0.f;

  for (int k0 = 0; k0 < K; k0 += 16) {
    // A tile: 64 rows x 16 k -> transposed As[k][m]; 256 float4, 1/thread
    {
      int row = t >> 2;   // 0..63
      int quad = t & 3;   // k sub-quad
      float4 v = {0.f, 0.f, 0.f, 0.f};
      int gr = m0 + row;
      if (gr < M) v = *(const float4*)&A[(size_t)gr * K + k0 + quad * 4];
      As[quad * 4 + 0][row] = v.x;
      As[quad * 4 + 1][row] = v.y;
      As[quad * 4 + 2][row] = v.z;
      As[quad * 4 + 3][row] = v.w;
    }
    // B tile: 16 k-rows x 128 cols; 512 float4, 2/thread
#pragma unroll
    for (int r = 0; r < 2; ++r) {
      int idx = t + r * 256;
      int krow = idx >> 5;  // 0..15
      int q = idx & 31;     // col quad
      float4 v = *(const float4*)&B[(size_t)(k0 + krow) * 256 + n0 + q * 4];
      *(float4*)&Bs[krow][q * 4] = v;
    }
    __syncthreads();
#pragma unroll
    for (int k = 0; k < 16; ++k) {
      float4 a0 = *(const float4*)&As[k][ty * 4];
      float4 b0 = *(const float4*)&Bs[k][tx * 4];
      float4 b1 = *(const float4*)&Bs[k][64 + tx * 4];
      float av[4] = {a0.x, a0.y, a0.z, a0.w};
      float bv[2][4] = {{b0.x, b0.y, b0.z, b0.w}, {b1.x, b1.y, b1.z, b1.w}};
#pragma unroll
      for (int jh = 0; jh < 2; ++jh)
#pragma unroll
        for (int i = 0; i < 4; ++i)
#pragma unroll
          for (int j = 0; j < 4; ++j)
            c[jh][i][j] += av[i] * bv[jh][j];
    }
    __syncthreads();
  }

  // ---- epilogue: h16 store + fused al (heads 2by, 2by+1), no pointers ----
  float4 asv0 = *(const float4*)&a_src[(by * 2 + 0) * 64 + tx * 4];
  float4 asv1 = *(const float4*)&a_src[(by * 2 + 1) * 64 + tx * 4];
  float4 adv0 = *(const float4*)&a_dst[(by * 2 + 0) * 64 + tx * 4];
  float4 adv1 = *(const float4*)&a_dst[(by * 2 + 1) * 64 + tx * 4];
#pragma unroll
  for (int i = 0; i < 4; ++i) {
    int gr = m0 + ty * 4 + i;
    float ps0 = c[0][i][0] * asv0.x + c[0][i][1] * asv0.y +
                c[0][i][2] * asv0.z + c[0][i][3] * asv0.w;
    float pd0 = c[0][i][0] * adv0.x + c[0][i][1] * adv0.y +
                c[0][i][2] * adv0.z + c[0][i][3] * adv0.w;
    float ps1 = c[1][i][0] * asv1.x + c[1][i][1] * asv1.y +
                c[1][i][2] * asv1.z + c[1][i][3] * asv1.w;
    float pd1 = c[1][i][0] * adv1.x + c[1][i][1] * adv1.y +
                c[1][i][2] * adv1.z + c[1][i][3] * adv1.w;
#pragma unroll
    for (int off = 1; off < 16; off <<= 1) {
      ps0 += __shfl_xor(ps0, off);
      pd0 += __shfl_xor(pd0, off);
      ps1 += __shfl_xor(ps1, off);
      pd1 += __shfl_xor(pd1, off);
    }
    if (gr < M) {
      h4 v0 = {(_Float16)c[0][i][0], (_Float16)c[0][i][1],
               (_Float16)c[0][i][2], (_Float16)c[0][i][3]};
      h4 v1 = {(_Float16)c[1][i][0], (_Float16)c[1][i][1],
               (_Float16)c[1][i][2], (_Float16)c[1][i][3]};
      *(h4*)&C16[(size_t)gr * 256 + n0 + tx * 4] = v0;
      *(h4*)&C16[(size_t)gr * 256 + n0 + 64 + tx * 4] = v1;
      if (tx == 0) {
        alS[gr * 4 + by * 2 + 0] = ps0;
        alS[gr * 4 + by * 2 + 1] = ps1;
        alD[gr * 4 + by * 2 + 0] = pd0;
        alD[gr * 4 + by * 2 + 1] = pd1;
      }
    }
  }
}

// ---------------- per-dst two-pass softmax aggregation (heads=4, C=64) ------

template <bool RELU>
__global__ __launch_bounds__(256) void gat_aggregate(
    const _Float16* __restrict__ h, const float* __restrict__ al_s,
    const float* __restrict__ al_d, const int* __restrict__ row_ptr,
    const int* __restrict__ col_idx, const float* __restrict__ bias,
    float* __restrict__ out, int nnodes) {
  __shared__ float e_lds[4][ECAP * 4];
  int wv = threadIdx.x >> 6;
  int n = blockIdx.x * 4 + wv;
  if (n >= nnodes) return;
  int l = threadIdx.x & 63;
  int hd = l >> 4;
  int sub = l & 15;
  int beg = row_ptr[n], end = row_ptr[n + 1];
  int deg = end - beg;
  float ad = al_d[n * 4 + hd];

  // ---- pass 1: logits + max ----
  float m = -3.0e38f;
  for (int j0 = 0; j0 < deg; j0 += 16) {
    int j = j0 + sub;
    float e = -3.0e38f;
    if (j < deg) {
      int src = col_idx[beg + j];
      e = al_s[src * 4 + hd] + ad;
      e = fmaxf(e, 0.2f * e);  // leaky_relu(0.2)
      if (j < ECAP) e_lds[wv][j * 4 + hd] = e;
    }
    m = fmaxf(m, e);
  }
#pragma unroll
  for (int off = 1; off < 16; off <<= 1) m = fmaxf(m, __shfl_xor(m, off));
  __syncthreads();

  // ---- pass 2: p = exp(e - m), fp16 gather-FMA, unrolled x8 ----
  float s = 0.f;
  float4 acc = {0.f, 0.f, 0.f, 0.f};
  int jcap = deg < ECAP ? deg : ECAP;
  int j = 0;
  for (; j + 8 <= jcap; j += 8) {
    int si[8];
    h4 hv[8];
    float p[8];
#pragma unroll
    for (int u = 0; u < 8; ++u) si[u] = col_idx[beg + j + u];
#pragma unroll
    for (int u = 0; u < 8; ++u)
      hv[u] = *(const h4*)&h[(size_t)si[u] * 256 + l * 4];
#pragma unroll
    for (int u = 0; u < 8; ++u) p[u] = __expf(e_lds[wv][(j + u) * 4 + hd] - m);
#pragma unroll
    for (int u = 0; u < 8; ++u) {
      s += p[u];
      acc.x += p[u] * (float)hv[u][0];
      acc.y += p[u] * (float)hv[u][1];
      acc.z += p[u] * (float)hv[u][2];
      acc.w += p[u] * (float)hv[u][3];
    }
  }
  for (; j < deg; ++j) {
    int src = col_idx[beg + j];
    float e;
    if (j < ECAP) {
      e = e_lds[wv][j * 4 + hd];
    } else {  // fallback for pathological degree
      e = al_s[src * 4 + hd] + ad;
      e = fmaxf(e, 0.2f * e);
    }
    float p = __expf(e - m);
    s += p;
    h4 hv = *(const h4*)&h[(size_t)src * 256 + l * 4];
    acc.x += p * (float)hv[0];
    acc.y += p * (float)hv[1];
    acc.z += p * (float)hv[2];
    acc.w += p * (float)hv[3];
  }
  float inv = 1.f / (s + 1e-16f);
  float4 bv = *(const float4*)&bias[l * 4];
  float4 o = {acc.x * inv + bv.x, acc.y * inv + bv.y, acc.z * inv + bv.z,
              acc.w * inv + bv.w};
  if (RELU) {
    o.x = fmaxf(o.x, 0.f);
    o.y = fmaxf(o.y, 0.f);
    o.z = fmaxf(o.z, 0.f);
    o.w = fmaxf(o.w, 0.f);
  }
  *(float4*)&out[(size_t)n * 256 + l * 4] = o;
}

// ---------------- layer 3: tiny GEMM (256->5) fused with al3 ----------------

__global__ __launch_bounds__(256) void gemm3_al(const float* __restrict__ Hin,
                                                const float* __restrict__ W3,
                                                const float* __restrict__ a_src3,
                                                const float* __restrict__ a_dst3,
                                                float* __restrict__ h3,
                                                float* __restrict__ al_s,
                                                float* __restrict__ al_d,
                                                int nnodes) {
  int n = blockIdx.x * 4 + (threadIdx.x >> 6);
  if (n >= nnodes) return;
  int l = threadIdx.x & 63;
  float4 hv = *(const float4*)&Hin[(size_t)n * 256 + l * 4];
  float acc[5];
#pragma unroll
  for (int cc = 0; cc < 5; ++cc) {
    acc[cc] = hv.x * W3[(l * 4 + 0) * 5 + cc] + hv.y * W3[(l * 4 + 1) * 5 + cc] +
              hv.z * W3[(l * 4 + 2) * 5 + cc] + hv.w * W3[(l * 4 + 3) * 5 + cc];
  }
#pragma unroll
  for (int cc = 0; cc < 5; ++cc)
#pragma unroll
    for (int off = 32; off; off >>= 1) acc[cc] += __shfl_xor(acc[cc], off);
  if (l == 0) {
    float as = 0.f, adv = 0.f;
#pragma unroll
    for (int cc = 0; cc < 5; ++cc) {
      h3[(size_t)n * 5 + cc] = acc[cc];
      as += acc[cc] * a_src3[cc];
      adv += acc[cc] * a_dst3[cc];
    }
    al_s[n] = as;
    al_d[n] = adv;
  }
}

// two-pass (parallel logits, no serial exp-rescale chain), heads=1, C=5

__global__ __launch_bounds__(256) void gat_aggregate3(
    const float* __restrict__ h3, const float* __restrict__ al_s,
    const float* __restrict__ al_d, const int* __restrict__ row_ptr,
    const int* __restrict__ col_idx, const float* __restrict__ b3,
    float* __restrict__ out, int nnodes) {
  __shared__ float e_lds[4][ECAP];
  int wv = threadIdx.x >> 6;
  int n = blockIdx.x * 4 + wv;
  if (n >= nnodes) return;
  int l = threadIdx.x & 63;
  int beg = row_ptr[n], end = row_ptr[n + 1];
  int deg = end - beg;
  float ad = al_d[n];

  // pass 1: all 64 lanes compute logits in parallel
  float m = -3.0e38f;
  for (int j0 = 0; j0 < deg; j0 += 64) {
    int j = j0 + l;
    float e = -3.0e38f;
    if (j < deg) {
      int src = col_idx[beg + j];
      e = al_s[src] + ad;
      e = fmaxf(e, 0.2f * e);
      if (j < ECAP) e_lds[wv][j] = e;
    }
    m = fmaxf(m, e);
  }
#pragma unroll
  for (int off = 1; off < 64; off <<= 1) m = fmaxf(m, __shfl_xor(m, off));

  // s: parallel partial sums over LDS/recomputed logits
  float sp = 0.f;
  for (int j = l; j < deg; j += 64) {
    float e;
    if (j < ECAP) {
      e = e_lds[wv][j];
    } else {
      int src = col_idx[beg + j];
      e = al_s[src] + ad;
      e = fmaxf(e, 0.2f * e);
    }
    sp += __expf(e - m);
  }
#pragma unroll
  for (int off = 1; off < 64; off <<= 1) sp += __shfl_xor(sp, off);
  float s = sp;

  // pass 2: lanes 0..4 gather h3 and accumulate (h3 is 1MB, L2-resident)
  float acc = 0.f;
  if (l < 5) {
    for (int j = 0; j < deg; ++j) {
      float e;
      if (j < ECAP) {
        e = e_lds[wv][j];
      } else {
        int src0 = col_idx[beg + j];
        e = al_s[src0] + ad;
        e = fmaxf(e, 0.2f * e);
      }
      float p = __expf(e - m);
      int src = col_idx[beg + j];
      acc += p * h3[(size_t)src * 5 + l];
    }
    out[(size_t)n * 5 + l] = acc / (s + 1e-16f) + b3[l];
  }
}

// ---------------- launch ----------------

extern "C" void kernel_launch(void* const* d_in, const int* in_sizes, int n_in,
                              void* d_out, int out_size, void* d_ws, size_t ws_size,
                              hipStream_t stream) {
  const float* x = (const float*)d_in[0];
  const int* ei = (const int*)d_in[1];
  const float* W1 = (const float*)d_in[2];
  const float* as1 = (const float*)d_in[3];
  const float* ad1 = (const float*)d_in[4];
  const float* b1 = (const float*)d_in[5];
  const float* W2 = (const float*)d_in[6];
  const float* as2 = (const float*)d_in[7];
  const float* ad2 = (const float*)d_in[8];
  const float* b2 = (const float*)d_in[9];
  const float* W3 = (const float*)d_in[10];
  const float* as3 = (const float*)d_in[11];
  const float* ad3 = (const float*)d_in[12];
  const float* b3 = (const float*)d_in[13];

  int N = in_sizes[0] / 128;  // 50000
  int E = in_sizes[1] / 2;    // 800000
  int tot = E + N;            // 850000

  char* w = (char*)d_ws;
  size_t off = 0;
  auto alloc = [&](size_t bytes) -> void* {
    void* p = w + off;
    off += (bytes + 255) & ~(size_t)255;
    return p;
  };
  _Float16* h16 = (_Float16*)alloc((size_t)N * 256 * 2);
  float* bufB = (float*)alloc((size_t)N * 256 * 4);
  float* bufC = (float*)alloc((size_t)N * 256 * 4);
  float* h3 = (float*)alloc((size_t)N * 5 * 4);
  float* alS = (float*)alloc((size_t)N * 4 * 4);
  float* alD = (float*)alloc((size_t)N * 4 * 4);
  int* row_ptr = (int*)alloc(((size_t)N + 1) * 4);
  int* nextp = (int*)alloc((size_t)N * 4);
  int* bsums = (int*)alloc(256 * 4);
  int* col_idx = (int*)alloc((size_t)tot * 4);
  (void)ws_size;

  int nbN = (N + 255) / 256;
  int nbE = (tot + 255) / 256;
  int nb4 = (N + 3) / 4;

  // CSR build (counts live in nextp)
  zero_i32<<<nbN, 256, 0, stream>>>(nextp, N);
  edge_histogram<<<nbE, 256, 0, stream>>>(ei, E, N, nextp);
  scan_block<<<nbN, 256, 0, stream>>>(nextp, row_ptr, bsums, N);
  scan_block<<<1, 256, 0, stream>>>(bsums, bsums, nullptr, nbN);
  add_offsets<<<nbN, 256, 0, stream>>>(row_ptr, bsums, nextp, N, tot);
  edge_scatter<<<nbE, 256, 0, stream>>>(ei, E, N, nextp, col_idx);

  dim3 g1((N + 63) / 64, 2);

  // layer 1
  gemm_al<<<g1, 256, 0, stream>>>(x, W1, h16, as1, ad1, alS, alD, N, 128);
  gat_aggregate<true><<<nb4, 256, 0, stream>>>(h16, alS, alD, row_ptr, col_idx,
                                               b1, bufB, N);
  // layer 2
  gemm_al<<<g1, 256, 0, stream>>>(bufB, W2, h16, as2, ad2, alS, alD, N, 256);
  gat_aggregate<true><<<nb4, 256, 0, stream>>>(h16, alS, alD, row_ptr, col_idx,
                                               b2, bufC, N);
  // layer 3
  gemm3_al<<<nb4, 256, 0, stream>>>(bufC, W3, as3, ad3, h3, alS, alD, N);
  gat_aggregate3<<<nb4, 256, 0, stream>>>(h3, alS, alD, row_ptr, col_idx, b3,
                                          (float*)d_out, N);
}

// Round 13
// 477.450 us; speedup vs baseline: 2.0478x; 2.0478x over previous
//
#include <hip/hip_runtime.h>
#include <hip/hip_bf16.h>
#include <cstddef>

// ---------------------------------------------------------------------------
// 3-layer GAT (PyG-style) on MI355X.
// Round 13: gemm_al inner loop moved to MFMA (v_mfma_f32_16x16x32_f16,
// fp32 accumulate). A and W cast fp32->fp16 during LDS staging; LDS tiles
// K-contiguous with B transposed ([col][k]) so A/B fragments load as
// ds_read_b128. Lane layouts: A/B = [l&15][(l>>4)*8+j]; D col=l&15,
// row=(l>>4)*4+reg (m89-verified). No launch_bounds cap (r12 spill lesson);
// b-frags loaded singly to keep VGPR < 128 (r11 occupancy lesson).
// h stored fp16 (gather at the 8-XCD private-L2 re-fetch floor, ~213MB).
// ---------------------------------------------------------------------------

typedef _Float16 h4 __attribute__((ext_vector_type(4)));
typedef _Float16 f16x4 __attribute__((ext_vector_type(4)));
typedef _Float16 f16x8 __attribute__((ext_vector_type(8)));
typedef float f32x4 __attribute__((ext_vector_type(4)));

#define ECAP 96  // LDS-cached logits per node; deg>ECAP falls back to re-gather
#define LSTR 40  // LDS K-stride in f16 (32 data + 8 pad -> bank spread)

// ---------------- CSR build ----------------

__global__ void zero_i32(int* __restrict__ p, int n) {
  int i = blockIdx.x * 256 + threadIdx.x;
  if (i < n) p[i] = 0;
}

__global__ void edge_histogram(const int* __restrict__ ei, int E, int nnodes,
                               int* __restrict__ counts) {
  int e = blockIdx.x * 256 + threadIdx.x;
  int tot = E + nnodes;
  if (e >= tot) return;
  int dst = (e < E) ? ei[E + e] : (e - E);
  atomicAdd(&counts[dst], 1);
}

__global__ void scan_block(const int* __restrict__ in, int* __restrict__ out,
                           int* __restrict__ sums, int n) {
  __shared__ int tmp[256];
  int i = blockIdx.x * 256 + threadIdx.x;
  int v = (i < n) ? in[i] : 0;
  tmp[threadIdx.x] = v;
  __syncthreads();
  for (int off = 1; off < 256; off <<= 1) {
    int t = (threadIdx.x >= off) ? tmp[threadIdx.x - off] : 0;
    __syncthreads();
    tmp[threadIdx.x] += t;
    __syncthreads();
  }
  if (i < n) out[i] = tmp[threadIdx.x] - v;  // exclusive
  if (sums && threadIdx.x == 255) sums[blockIdx.x] = tmp[255];
}

__global__ void add_offsets(int* __restrict__ row_ptr, const int* __restrict__ offs,
                            int* __restrict__ nextp, int n, int total) {
  int i = blockIdx.x * 256 + threadIdx.x;
  if (i < n) {
    int v = row_ptr[i] + offs[blockIdx.x];
    row_ptr[i] = v;
    nextp[i] = v;
  }
  if (i == 0) row_ptr[n] = total;
}

__global__ void edge_scatter(const int* __restrict__ ei, int E, int nnodes,
                             int* __restrict__ nextp, int* __restrict__ col_idx) {
  int e = blockIdx.x * 256 + threadIdx.x;
  int tot = E + nnodes;
  if (e >= tot) return;
  int src = (e < E) ? ei[e] : (e - E);
  int dst = (e < E) ? ei[E + e] : (e - E);
  int pos = atomicAdd(&nextp[dst], 1);
  col_idx[pos] = src;
}

// ---------------- fused MFMA GEMM + al: h16 = A@B, al_s/al_d ---------------
// N fixed 256. BM=128, BN=128 (2 heads), KB=32, 256 threads = 4 waves (2x2),
// each wave owns a 64x64 output = 4x4 tiles of 16x16x32 MFMA.

__global__ __launch_bounds__(256) void gemm_al(
    const float* __restrict__ A, const float* __restrict__ B,
    _Float16* __restrict__ C16, const float* __restrict__ a_src,
    const float* __restrict__ a_dst, float* __restrict__ alS,
    float* __restrict__ alD, int M, int K) {
  __shared__ _Float16 As16[128][LSTR];
  __shared__ _Float16 Bs16[128][LSTR];
  int t = threadIdx.x;
  int m0 = blockIdx.x * 128;
  int by = blockIdx.y;
  int n0 = by * 128;

  int l = t & 63;
  int w = t >> 6;
  int wr = w >> 1, wc = w & 1;
  int lr = l & 15;          // row (A) / col (B) within 16-tile
  int lk = (l >> 4) * 8;    // k base within 32

  // B staging decomposition: thread -> (col, k-half)
  int colB = t & 127;
  int kqB = t >> 7;  // 0..1, covers k = kqB*16 .. +15

  f32x4 acc[4][4];
#pragma unroll
  for (int i = 0; i < 4; ++i)
#pragma unroll
    for (int j = 0; j < 4; ++j) acc[i][j] = (f32x4){0.f, 0.f, 0.f, 0.f};

  const float4 f40 = {0.f, 0.f, 0.f, 0.f};
  for (int k0 = 0; k0 < K; k0 += 32) {
    // A tile: 128 rows x 32 k, fp32 -> fp16, row-major K-contig
#pragma unroll
    for (int r = 0; r < 4; ++r) {
      int idx = t + r * 256;   // 0..1023
      int row = idx >> 3;      // 0..127
      int q = idx & 7;         // k quad
      int gr = m0 + row;
      float4 v = (gr < M) ? *(const float4*)&A[(size_t)gr * K + k0 + q * 4]
                          : f40;
      f16x4 hv = {(_Float16)v.x, (_Float16)v.y, (_Float16)v.z, (_Float16)v.w};
      *(f16x4*)&As16[row][q * 4] = hv;
    }
    // B tile: 32 k x 128 cols, transposed into Bs16[col][k], fp32 -> fp16
#pragma unroll
    for (int half = 0; half < 2; ++half) {
      f16x8 hv;
#pragma unroll
      for (int j = 0; j < 8; ++j) {
        int k = kqB * 16 + half * 8 + j;
        hv[j] = (_Float16)B[(size_t)(k0 + k) * 256 + n0 + colB];
      }
      *(f16x8*)&Bs16[colB][kqB * 16 + half * 8] = hv;
    }
    __syncthreads();
    // fragments + MFMA: a-frags held, b-frags streamed (VGPR liveness)
    f16x8 af0 = *(const f16x8*)&As16[wr * 64 + 0 * 16 + lr][lk];
    f16x8 af1 = *(const f16x8*)&As16[wr * 64 + 1 * 16 + lr][lk];
    f16x8 af2 = *(const f16x8*)&As16[wr * 64 + 2 * 16 + lr][lk];
    f16x8 af3 = *(const f16x8*)&As16[wr * 64 + 3 * 16 + lr][lk];
#pragma unroll
    for (int j = 0; j < 4; ++j) {
      f16x8 bf = *(const f16x8*)&Bs16[wc * 64 + j * 16 + lr][lk];
      acc[0][j] = __builtin_amdgcn_mfma_f32_16x16x32_f16(af0, bf, acc[0][j], 0, 0, 0);
      acc[1][j] = __builtin_amdgcn_mfma_f32_16x16x32_f16(af1, bf, acc[1][j], 0, 0, 0);
      acc[2][j] = __builtin_amdgcn_mfma_f32_16x16x32_f16(af2, bf, acc[2][j], 0, 0, 0);
      acc[3][j] = __builtin_amdgcn_mfma_f32_16x16x32_f16(af3, bf, acc[3][j], 0, 0, 0);
    }
    __syncthreads();
  }

  // ---- epilogue: h16 store + fused al (head = by*2 + wc) ----
  int head = by * 2 + wc;
  float as4[4], ad4[4];
#pragma unroll
  for (int j = 0; j < 4; ++j) {
    as4[j] = a_src[head * 64 + j * 16 + lr];
    ad4[j] = a_dst[head * 64 + j * 16 + lr];
  }
#pragma unroll
  for (int i = 0; i < 4; ++i) {
#pragma unroll
    for (int reg = 0; reg < 4; ++reg) {
      int gr = m0 + wr * 64 + i * 16 + (l >> 4) * 4 + reg;
      float ps = acc[i][0][reg] * as4[0] + acc[i][1][reg] * as4[1] +
                 acc[i][2][reg] * as4[2] + acc[i][3][reg] * as4[3];
      float pd = acc[i][0][reg] * ad4[0] + acc[i][1][reg] * ad4[1] +
                 acc[i][2][reg] * ad4[2] + acc[i][3][reg] * ad4[3];
#pragma unroll
      for (int off = 1; off < 16; off <<= 1) {
        ps += __shfl_xor(ps, off);
        pd += __shfl_xor(pd, off);
      }
      if (gr < M) {
#pragma unroll
        for (int j = 0; j < 4; ++j)
          C16[(size_t)gr * 256 + n0 + wc * 64 + j * 16 + lr] =
              (_Float16)acc[i][j][reg];
        if (lr == 0) {
          alS[gr * 4 + head] = ps;
          alD[gr * 4 + head] = pd;
        }
      }
    }
  }
}

// ---------------- per-dst two-pass softmax aggregation (heads=4, C=64) ------

template <bool RELU>
__global__ __launch_bounds__(256) void gat_aggregate(
    const _Float16* __restrict__ h, const float* __restrict__ al_s,
    const float* __restrict__ al_d, const int* __restrict__ row_ptr,
    const int* __restrict__ col_idx, const float* __restrict__ bias,
    float* __restrict__ out, int nnodes) {
  __shared__ float e_lds[4][ECAP * 4];
  int wv = threadIdx.x >> 6;
  int n = blockIdx.x * 4 + wv;
  if (n >= nnodes) return;
  int l = threadIdx.x & 63;
  int hd = l >> 4;
  int sub = l & 15;
  int beg = row_ptr[n], end = row_ptr[n + 1];
  int deg = end - beg;
  float ad = al_d[n * 4 + hd];

  // ---- pass 1: logits + max ----
  float m = -3.0e38f;
  for (int j0 = 0; j0 < deg; j0 += 16) {
    int j = j0 + sub;
    float e = -3.0e38f;
    if (j < deg) {
      int src = col_idx[beg + j];
      e = al_s[src * 4 + hd] + ad;
      e = fmaxf(e, 0.2f * e);  // leaky_relu(0.2)
      if (j < ECAP) e_lds[wv][j * 4 + hd] = e;
    }
    m = fmaxf(m, e);
  }
#pragma unroll
  for (int off = 1; off < 16; off <<= 1) m = fmaxf(m, __shfl_xor(m, off));
  __syncthreads();

  // ---- pass 2: p = exp(e - m), fp16 gather-FMA, unrolled x8 ----
  float s = 0.f;
  float4 acc = {0.f, 0.f, 0.f, 0.f};
  int jcap = deg < ECAP ? deg : ECAP;
  int j = 0;
  for (; j + 8 <= jcap; j += 8) {
    int si[8];
    h4 hv[8];
    float p[8];
#pragma unroll
    for (int u = 0; u < 8; ++u) si[u] = col_idx[beg + j + u];
#pragma unroll
    for (int u = 0; u < 8; ++u)
      hv[u] = *(const h4*)&h[(size_t)si[u] * 256 + l * 4];
#pragma unroll
    for (int u = 0; u < 8; ++u) p[u] = __expf(e_lds[wv][(j + u) * 4 + hd] - m);
#pragma unroll
    for (int u = 0; u < 8; ++u) {
      s += p[u];
      acc.x += p[u] * (float)hv[u][0];
      acc.y += p[u] * (float)hv[u][1];
      acc.z += p[u] * (float)hv[u][2];
      acc.w += p[u] * (float)hv[u][3];
    }
  }
  for (; j < deg; ++j) {
    int src = col_idx[beg + j];
    float e;
    if (j < ECAP) {
      e = e_lds[wv][j * 4 + hd];
    } else {  // fallback for pathological degree
      e = al_s[src * 4 + hd] + ad;
      e = fmaxf(e, 0.2f * e);
    }
    float p = __expf(e - m);
    s += p;
    h4 hv = *(const h4*)&h[(size_t)src * 256 + l * 4];
    acc.x += p * (float)hv[0];
    acc.y += p * (float)hv[1];
    acc.z += p * (float)hv[2];
    acc.w += p * (float)hv[3];
  }
  float inv = 1.f / (s + 1e-16f);
  float4 bv = *(const float4*)&bias[l * 4];
  float4 o = {acc.x * inv + bv.x, acc.y * inv + bv.y, acc.z * inv + bv.z,
              acc.w * inv + bv.w};
  if (RELU) {
    o.x = fmaxf(o.x, 0.f);
    o.y = fmaxf(o.y, 0.f);
    o.z = fmaxf(o.z, 0.f);
    o.w = fmaxf(o.w, 0.f);
  }
  *(float4*)&out[(size_t)n * 256 + l * 4] = o;
}

// ---------------- layer 3: tiny GEMM (256->5) fused with al3 ----------------

__global__ __launch_bounds__(256) void gemm3_al(const float* __restrict__ Hin,
                                                const float* __restrict__ W3,
                                                const float* __restrict__ a_src3,
                                                const float* __restrict__ a_dst3,
                                                float* __restrict__ h3,
                                                float* __restrict__ al_s,
                                                float* __restrict__ al_d,
                                                int nnodes) {
  int n = blockIdx.x * 4 + (threadIdx.x >> 6);
  if (n >= nnodes) return;
  int l = threadIdx.x & 63;
  float4 hv = *(const float4*)&Hin[(size_t)n * 256 + l * 4];
  float acc[5];
#pragma unroll
  for (int cc = 0; cc < 5; ++cc) {
    acc[cc] = hv.x * W3[(l * 4 + 0) * 5 + cc] + hv.y * W3[(l * 4 + 1) * 5 + cc] +
              hv.z * W3[(l * 4 + 2) * 5 + cc] + hv.w * W3[(l * 4 + 3) * 5 + cc];
  }
#pragma unroll
  for (int cc = 0; cc < 5; ++cc)
#pragma unroll
    for (int off = 32; off; off >>= 1) acc[cc] += __shfl_xor(acc[cc], off);
  if (l == 0) {
    float as = 0.f, adv = 0.f;
#pragma unroll
    for (int cc = 0; cc < 5; ++cc) {
      h3[(size_t)n * 5 + cc] = acc[cc];
      as += acc[cc] * a_src3[cc];
      adv += acc[cc] * a_dst3[cc];
    }
    al_s[n] = as;
    al_d[n] = adv;
  }
}

// two-pass (parallel logits, no serial exp-rescale chain), heads=1, C=5

__global__ __launch_bounds__(256) void gat_aggregate3(
    const float* __restrict__ h3, const float* __restrict__ al_s,
    const float* __restrict__ al_d, const int* __restrict__ row_ptr,
    const int* __restrict__ col_idx, const float* __restrict__ b3,
    float* __restrict__ out, int nnodes) {
  __shared__ float e_lds[4][ECAP];
  int wv = threadIdx.x >> 6;
  int n = blockIdx.x * 4 + wv;
  if (n >= nnodes) return;
  int l = threadIdx.x & 63;
  int beg = row_ptr[n], end = row_ptr[n + 1];
  int deg = end - beg;
  float ad = al_d[n];

  // pass 1: all 64 lanes compute logits in parallel
  float m = -3.0e38f;
  for (int j0 = 0; j0 < deg; j0 += 64) {
    int j = j0 + l;
    float e = -3.0e38f;
    if (j < deg) {
      int src = col_idx[beg + j];
      e = al_s[src] + ad;
      e = fmaxf(e, 0.2f * e);
      if (j < ECAP) e_lds[wv][j] = e;
    }
    m = fmaxf(m, e);
  }
#pragma unroll
  for (int off = 1; off < 64; off <<= 1) m = fmaxf(m, __shfl_xor(m, off));

  // s: parallel partial sums over LDS/recomputed logits
  float sp = 0.f;
  for (int j = l; j < deg; j += 64) {
    float e;
    if (j < ECAP) {
      e = e_lds[wv][j];
    } else {
      int src = col_idx[beg + j];
      e = al_s[src] + ad;
      e = fmaxf(e, 0.2f * e);
    }
    sp += __expf(e - m);
  }
#pragma unroll
  for (int off = 1; off < 64; off <<= 1) sp += __shfl_xor(sp, off);
  float s = sp;

  // pass 2: lanes 0..4 gather h3 and accumulate (h3 is 1MB, L2-resident)
  float acc = 0.f;
  if (l < 5) {
    for (int j = 0; j < deg; ++j) {
      float e;
      if (j < ECAP) {
        e = e_lds[wv][j];
      } else {
        int src0 = col_idx[beg + j];
        e = al_s[src0] + ad;
        e = fmaxf(e, 0.2f * e);
      }
      float p = __expf(e - m);
      int src = col_idx[beg + j];
      acc += p * h3[(size_t)src * 5 + l];
    }
    out[(size_t)n * 5 + l] = acc / (s + 1e-16f) + b3[l];
  }
}

// ---------------- launch ----------------

extern "C" void kernel_launch(void* const* d_in, const int* in_sizes, int n_in,
                              void* d_out, int out_size, void* d_ws, size_t ws_size,
                              hipStream_t stream) {
  const float* x = (const float*)d_in[0];
  const int* ei = (const int*)d_in[1];
  const float* W1 = (const float*)d_in[2];
  const float* as1 = (const float*)d_in[3];
  const float* ad1 = (const float*)d_in[4];
  const float* b1 = (const float*)d_in[5];
  const float* W2 = (const float*)d_in[6];
  const float* as2 = (const float*)d_in[7];
  const float* ad2 = (const float*)d_in[8];
  const float* b2 = (const float*)d_in[9];
  const float* W3 = (const float*)d_in[10];
  const float* as3 = (const float*)d_in[11];
  const float* ad3 = (const float*)d_in[12];
  const float* b3 = (const float*)d_in[13];

  int N = in_sizes[0] / 128;  // 50000
  int E = in_sizes[1] / 2;    // 800000
  int tot = E + N;            // 850000

  char* w = (char*)d_ws;
  size_t off = 0;
  auto alloc = [&](size_t bytes) -> void* {
    void* p = w + off;
    off += (bytes + 255) & ~(size_t)255;
    return p;
  };
  _Float16* h16 = (_Float16*)alloc((size_t)N * 256 * 2);
  float* bufB = (float*)alloc((size_t)N * 256 * 4);
  float* bufC = (float*)alloc((size_t)N * 256 * 4);
  float* h3 = (float*)alloc((size_t)N * 5 * 4);
  float* alS = (float*)alloc((size_t)N * 4 * 4);
  float* alD = (float*)alloc((size_t)N * 4 * 4);
  int* row_ptr = (int*)alloc(((size_t)N + 1) * 4);
  int* nextp = (int*)alloc((size_t)N * 4);
  int* bsums = (int*)alloc(256 * 4);
  int* col_idx = (int*)alloc((size_t)tot * 4);
  (void)ws_size;

  int nbN = (N + 255) / 256;
  int nbE = (tot + 255) / 256;
  int nb4 = (N + 3) / 4;

  // CSR build (counts live in nextp)
  zero_i32<<<nbN, 256, 0, stream>>>(nextp, N);
  edge_histogram<<<nbE, 256, 0, stream>>>(ei, E, N, nextp);
  scan_block<<<nbN, 256, 0, stream>>>(nextp, row_ptr, bsums, N);
  scan_block<<<1, 256, 0, stream>>>(bsums, bsums, nullptr, nbN);
  add_offsets<<<nbN, 256, 0, stream>>>(row_ptr, bsums, nextp, N, tot);
  edge_scatter<<<nbE, 256, 0, stream>>>(ei, E, N, nextp, col_idx);

  dim3 g1((N + 127) / 128, 2);

  // layer 1
  gemm_al<<<g1, 256, 0, stream>>>(x, W1, h16, as1, ad1, alS, alD, N, 128);
  gat_aggregate<true><<<nb4, 256, 0, stream>>>(h16, alS, alD, row_ptr, col_idx,
                                               b1, bufB, N);
  // layer 2
  gemm_al<<<g1, 256, 0, stream>>>(bufB, W2, h16, as2, ad2, alS, alD, N, 256);
  gat_aggregate<true><<<nb4, 256, 0, stream>>>(h16, alS, alD, row_ptr, col_idx,
                                               b2, bufC, N);
  // layer 3
  gemm3_al<<<nb4, 256, 0, stream>>>(bufC, W3, as3, ad3, h3, alS, alD, N);
  gat_aggregate3<<<nb4, 256, 0, stream>>>(h3, alS, alD, row_ptr, col_idx, b3,
                                          (float*)d_out, N);
}